// Round 21
// baseline (1873.096 us; speedup 1.0000x reference)
//
#include <hip/hip_runtime.h>
#include <math.h>

#define NN 512
#define TSEQ 12
#define BB 64

typedef unsigned short u16;
typedef short s16x4 __attribute__((ext_vector_type(4)));
typedef short s16x8 __attribute__((ext_vector_type(8)));
typedef float f32x4 __attribute__((ext_vector_type(4)));

__device__ __forceinline__ float b2f(u16 h) { return __uint_as_float(((unsigned)h) << 16); }
__device__ __forceinline__ u16 f2b(float f) {
    unsigned u = __float_as_uint(f);
    return (u16)((u + 0x7FFFu + ((u >> 16) & 1u)) >> 16);
}

// ---------------- workspace layout (bytes) ----------------
constexpr size_t SZP    = (size_t)512 * 4096 * 2;   // one state plane (4 MB)
constexpr size_t B_ADJ  = 0;
constexpr size_t B_DD   = B_ADJ + 524288;
constexpr size_t B_NRM  = B_DD + 2048;
constexpr size_t B_LMAX = B_NRM + 2048;
constexpr size_t B_XSH  = B_LMAX + 256;
constexpr size_t B_XSL  = B_XSH + 786432;
constexpr size_t B_TXH  = B_XSL + 786432;
constexpr size_t B_TXL  = B_TXH + 786432;
constexpr size_t B_ST   = B_TXL + 786432;           // 12 planes
constexpr size_t B_RBUF = B_ST + 12 * SZP;
constexpr size_t B_G0TH = B_RBUF + 8388608;
constexpr size_t B_G0TL = B_G0TH + 16777216;
constexpr size_t B_U0TH = B_G0TL + 16777216;
constexpr size_t B_U0TL = B_U0TH + 8388608;
constexpr size_t B_G1TH = B_U0TL + 8388608;
constexpr size_t B_G1TL = B_G1TH + 33554432;
constexpr size_t B_U1TH = B_G1TL + 33554432;
constexpr size_t B_U1TL = B_U1TH + 16777216;
constexpr size_t B_BG0  = B_U1TL + 16777216;
constexpr size_t B_BU0  = B_BG0 + 262144;
constexpr size_t B_BG1  = B_BU0 + 131072;
constexpr size_t B_BU1  = B_BG1 + 262144;
constexpr size_t B_G0X  = B_BU1 + 131072;
constexpr size_t B_U0X  = B_G0X + 524288;
constexpr size_t WS_BYTES = B_U0X + 262144;         // ~205 MiB

// ---------------- setup kernels ----------------

__global__ void k_marker(float* out, float v) { out[threadIdx.x] = v; }

__global__ void k_norm(const float* __restrict__ E, float* __restrict__ nrm) {
    int n = blockIdx.x * blockDim.x + threadIdx.x;
    if (n < NN) {
        float s = 0.f;
        #pragma unroll
        for (int q = 0; q < 10; ++q) { float e = E[n * 10 + q]; s += e * e; }
        nrm[n] = sqrtf(s);
    }
}

__global__ __launch_bounds__(256) void k_adj(const float* __restrict__ E, const float* __restrict__ gn,
                                             const float* __restrict__ nrm, u16* __restrict__ adjb,
                                             float* __restrict__ dd) {
    __shared__ float En[10];
    __shared__ float red[256];
    int n = blockIdx.x, tid = threadIdx.x;
    if (tid < 10) En[tid] = E[n * 10 + tid];
    __syncthreads();
    float nn = nrm[n];
    float cnt = 0.f;
    for (int m = tid; m < NN; m += 256) {
        float dot = 0.f;
        #pragma unroll
        for (int q = 0; q < 10; ++q) dot += En[q] * E[m * 10 + q];
        float lg = dot / (nn * nrm[m]);
        lg = (lg + 1.f) * 0.5f;
        float g0 = gn[((size_t)n * NN + m) * 2 + 0];
        float g1 = gn[((size_t)n * NN + m) * 2 + 1];
        bool a = ((lg + g0) >= (1.f - lg + g1) && (m != n));
        adjb[(size_t)n * NN + m] = a ? 0x3F80 : 0;
        cnt += a ? 1.f : 0.f;
    }
    red[tid] = cnt;
    __syncthreads();
    for (int s = 128; s > 0; s >>= 1) { if (tid < s) red[tid] += red[tid + s]; __syncthreads(); }
    if (tid == 0) dd[n] = red[0];
}

__global__ void k_dmax(const float* __restrict__ dd, float* __restrict__ lmax) {
    __shared__ float red[512];
    int t = threadIdx.x;
    red[t] = dd[t];
    __syncthreads();
    for (int s = 256; s > 0; s >>= 1) { if (t < s) red[t] = fmaxf(red[t], red[t + s]); __syncthreads(); }
    if (t == 0) lmax[0] = red[0] + (red[0] > 0.f ? 1.f : 0.f);
}

__global__ __launch_bounds__(256) void k_xs_bf(const float* __restrict__ gts, u16* __restrict__ xh,
                                               u16* __restrict__ xl) {
    int idx = blockIdx.x * 256 + threadIdx.x;
    if (idx >= NN * TSEQ * BB) return;
    int n = idx / (TSEQ * BB);
    int rem = idx - n * (TSEQ * BB);
    int t = rem >> 6, b = rem & 63;
    float v = gts[((size_t)b * NN + n) * TSEQ + t];
    u16 hb = f2b(v);
    xh[idx] = hb;
    xl[idx] = f2b(v - b2f(hb));
}

// ---------------- embed v3 (round-16): Wp in LDS + fragment-major output ----------------
template <int K2, int O, bool SHIFT>
__global__ __launch_bounds__(256) void k_embed2(const float* __restrict__ E, const float* __restrict__ Wp,
                                                u16* __restrict__ oh, u16* __restrict__ ol) {
    constexpr int KR = SHIFT ? 130 : K2;
    constexpr int NKB = K2 / 32;
    __shared__ float WpL[10][32][33];
    __shared__ float eL[16][10];
    const int nc = blockIdx.x, kc = blockIdx.y, oc = blockIdx.z;
    const int tid = threadIdx.x;
    const int rb = kc * 32 + (SHIFT ? (kc >= 2 ? 2 : 1) : 0);
    const int ocol = oc * 32;
    const int n0 = nc * 16;

    for (int el = tid; el < 10 * 32 * 32; el += 256) {
        int d = el >> 10;
        int rem = el & 1023;
        int k = rem >> 5, o = rem & 31;
        WpL[d][k][o] = Wp[((size_t)d * KR + rb + k) * O + ocol + o];
    }
    if (tid < 160) eL[tid / 10][tid % 10] = E[(n0 + tid / 10) * 10 + tid % 10];
    __syncthreads();

    const int o2 = tid >> 3;
    const int kv = (tid & 7) * 4;
    const int o = ocol + o2;
    const int lane = ((kv >> 3) << 4) + (o & 15);
    const size_t fragbase =
        ((((size_t)0 * (O / 16) + (o >> 4)) * NKB + kc) * 64 + lane) * 8 + (kv & 7);
    const size_t nstride = (size_t)(O / 16) * NKB * 64 * 8;

    for (int ni = 0; ni < 16; ++ni) {
        float ev[10];
        #pragma unroll
        for (int d = 0; d < 10; ++d) ev[d] = eL[ni][d];
        u16 ph[4], pl[4];
        #pragma unroll
        for (int j = 0; j < 4; ++j) {
            float a = 0.f;
            #pragma unroll
            for (int d = 0; d < 10; ++d) a += ev[d] * WpL[d][kv + j][o2];
            u16 hb = f2b(a);
            ph[j] = hb;
            pl[j] = f2b(a - b2f(hb));
        }
        size_t off = fragbase + (size_t)(n0 + ni) * nstride;
        *(s16x4*)&oh[off] = *(s16x4*)ph;
        *(s16x4*)&ol[off] = *(s16x4*)pl;
    }
}

__global__ __launch_bounds__(256) void k_bias(const float* __restrict__ E, const float* __restrict__ gb0,
                                              const float* __restrict__ ub0, const float* __restrict__ gb1,
                                              const float* __restrict__ ub1, const float* __restrict__ gw0,
                                              const float* __restrict__ uw0,
                                              float* BG0, float* BU0, float* BG1, float* BU1,
                                              float* G0X, float* U0X) {
    __shared__ float e[10];
    int n = blockIdx.x, tid = threadIdx.x;
    if (tid < 10) e[tid] = E[n * 10 + tid];
    __syncthreads();
    if (tid < 128) {
        int o = tid;
        float a0 = 0, a1 = 0, a2 = 0, a3 = 0;
        #pragma unroll
        for (int d = 0; d < 10; ++d) {
            a0 += e[d] * gb0[d * 128 + o];
            a1 += e[d] * gb1[d * 128 + o];
            a2 += e[d] * gw0[((size_t)d * 130 + 0) * 128 + o];
            a3 += e[d] * gw0[((size_t)d * 130 + 65) * 128 + o];
        }
        BG0[n * 128 + o] = a0; BG1[n * 128 + o] = a1;
        G0X[n * 256 + o] = a2; G0X[n * 256 + 128 + o] = a3;
    } else if (tid < 192) {
        int o = tid - 128;
        float a0 = 0, a1 = 0, a2 = 0, a3 = 0;
        #pragma unroll
        for (int d = 0; d < 10; ++d) {
            a0 += e[d] * ub0[d * 64 + o];
            a1 += e[d] * ub1[d * 64 + o];
            a2 += e[d] * uw0[((size_t)d * 130 + 0) * 64 + o];
            a3 += e[d] * uw0[((size_t)d * 130 + 65) * 64 + o];
        }
        BU0[n * 64 + o] = a0; BU1[n * 64 + o] = a1;
        U0X[n * 128 + o] = a2; U0X[n * 128 + 64 + o] = a3;
    }
}

// ---------------- gmm: ROUND 21 — 32x64 tiles, 1024 blocks (4/CU) ----------------
// A-side halves (A = 512KB L2-resident adjacency: extra re-reads are free); the
// B-path swizzle (the risky machinery) is byte-identical to round 17/20. Per-output
// k-window sequence and 2-MFMA-per-window order unchanged -> bit-identical.
struct GmmS {
    u16 As[2][32][72];
    u16 Bsh[2][2][64][32];
    u16 Bsl[2][2][64][32];
};

__device__ __forceinline__ void d_gmm(int by, int bx_, int tid,
                                      const u16* __restrict__ A, const u16* __restrict__ Bh,
                                      const u16* __restrict__ Bl, const float* __restrict__ dd,
                                      const float* __restrict__ lmax,
                                      u16* __restrict__ Ch, u16* __restrict__ Cl, int N, GmmS& S) {
    const int w = tid >> 6, l = tid & 63, lr = l & 15, lg = l >> 4;
    const int bm = by * 32, bn = bx_ * 64;
    const int am = tid >> 3, ak = (tid & 7) * 8;      // 32 rows x 64 k, 1 s16x8/thread
    const int bk = tid >> 3, bn8 = (tid & 7) * 8;
    const int bx = (tid & 7) & 3;
    const int col = ((bk >> 3) ^ bx) * 8 + (bk & 7);
    f32x4 acc[2];
    #pragma unroll
    for (int a = 0; a < 2; ++a) acc[a] = (f32x4){0.f, 0.f, 0.f, 0.f};

    const int nl = w * 16 + lr;
    const int cc = (lg ^ ((nl >> 3) & 3)) * 8;
    const size_t arow = (size_t)(bm + am) * 512;

    s16x8 rA0, rBh[2], rBl[2];
    rA0 = *(const s16x8*)&A[arow + 0 + ak];
    #pragma unroll
    for (int hh = 0; hh < 2; ++hh) {
        rBh[hh] = *(const s16x8*)&Bh[(size_t)(0 + hh * 32 + bk) * N + bn + bn8];
        rBl[hh] = *(const s16x8*)&Bl[(size_t)(0 + hh * 32 + bk) * N + bn + bn8];
    }
    *(s16x8*)&S.As[0][am][ak] = rA0;
    #pragma unroll
    for (int hh = 0; hh < 2; ++hh) {
        #pragma unroll
        for (int q = 0; q < 8; ++q) {
            S.Bsh[0][hh][bn8 + q][col] = ((const u16*)&rBh[hh])[q];
            S.Bsl[0][hh][bn8 + q][col] = ((const u16*)&rBl[hh])[q];
        }
    }
    __syncthreads();

    for (int k0 = 0; k0 < 512; k0 += 64) {
        const int cur = (k0 >> 6) & 1;
        const bool more = (k0 + 64 < 512);
        if (more) {
            rA0 = *(const s16x8*)&A[arow + k0 + 64 + ak];
            #pragma unroll
            for (int hh = 0; hh < 2; ++hh) {
                rBh[hh] = *(const s16x8*)&Bh[(size_t)(k0 + 64 + hh * 32 + bk) * N + bn + bn8];
                rBl[hh] = *(const s16x8*)&Bl[(size_t)(k0 + 64 + hh * 32 + bk) * N + bn + bn8];
            }
        }
        #pragma unroll
        for (int hh = 0; hh < 2; ++hh) {
            s16x8 bfh = *(const s16x8*)&S.Bsh[cur][hh][nl][cc];
            s16x8 bfl = *(const s16x8*)&S.Bsl[cur][hh][nl][cc];
            #pragma unroll
            for (int mf = 0; mf < 2; ++mf) {
                s16x8 afr = *(const s16x8*)&S.As[cur][mf * 16 + lr][hh * 32 + lg * 8];
                acc[mf] = __builtin_amdgcn_mfma_f32_16x16x32_bf16(afr, bfh, acc[mf], 0, 0, 0);
                acc[mf] = __builtin_amdgcn_mfma_f32_16x16x32_bf16(afr, bfl, acc[mf], 0, 0, 0);
            }
        }
        if (more) {
            const int nxt = cur ^ 1;
            *(s16x8*)&S.As[nxt][am][ak] = rA0;
            #pragma unroll
            for (int hh = 0; hh < 2; ++hh) {
                #pragma unroll
                for (int q = 0; q < 8; ++q) {
                    S.Bsh[nxt][hh][bn8 + q][col] = ((const u16*)&rBh[hh])[q];
                    S.Bsl[nxt][hh][bn8 + q][col] = ((const u16*)&rBl[hh])[q];
                }
            }
        }
        __syncthreads();
    }
    const float lm = lmax[0], alpha = -2.f / lm;
    const int colg = bn + w * 16 + lr;
    #pragma unroll
    for (int mf = 0; mf < 2; ++mf) {
        #pragma unroll
        for (int i = 0; i < 4; ++i) {
            int rowg = bm + mf * 16 + lg * 4 + i;
            size_t off = (size_t)rowg * N + colg;
            float hval = b2f(Bh[off]) + b2f(Bl[off]);
            float beta = 2.f * dd[rowg] / lm - 1.f;
            float v = alpha * acc[mf][i] + beta * hval;
            u16 hb = f2b(v);
            Ch[off] = hb;
            Cl[off] = f2b(v - b2f(hb));
        }
    }
}

__global__ __launch_bounds__(256) void k_gmm(const u16* __restrict__ A, const u16* __restrict__ Bh,
                                             const u16* __restrict__ Bl, const float* __restrict__ dd,
                                             const float* __restrict__ lmax,
                                             u16* __restrict__ Ch, u16* __restrict__ Cl, int N) {
    __shared__ GmmS S;
    d_gmm(blockIdx.y, blockIdx.x, threadIdx.x, A, Bh, Bl, dd, lmax, Ch, Cl, N, S);
}

// ---------------- split-precision MFMA cells ----------------
struct CellP {
    const u16 *s0h, *s0l, *s1h, *s1l, *s2h, *s2l, *s3h, *s3l;
    const u16 *Wh, *Wl;
    const float *bias, *wx;
    const u16 *xsh, *xsl, *txh, *txl;
    const u16 *hph, *hpl;
    float* rbuf;
    u16 *oh, *ol;
    int xoff;
};

// UPDATE cell split by batch-half (round-20 verified)
template <int K2, bool RANK1>
__device__ __forceinline__ void d_cellu2(int n, int mhalf, int tid, const CellP& p) {
    constexpr int NKB = K2 / 32;
    const int w = tid >> 6, l = tid & 63, lr = l & 15, lg = l >> 4;
    const int mf = mhalf * 2 + (w >> 1);
    const int nbase = (w & 1) * 2;
    f32x4 acc[2];
    #pragma unroll
    for (int c = 0; c < 2; ++c) acc[c] = (f32x4){0.f, 0.f, 0.f, 0.f};
    const size_t nb = (size_t)n * 4096;

    #pragma unroll
    for (int kb = 0; kb < NKB; ++kb) {
        const int sg = kb >> 1;
        const u16* sh = sg == 0 ? p.s0h : sg == 1 ? p.s1h : sg == 2 ? p.s2h : p.s3h;
        const u16* sl = sg == 0 ? p.s0l : sg == 1 ? p.s1l : sg == 2 ? p.s2l : p.s3l;
        const int koff = (kb & 1) * 32 + lg * 8;
        s16x8 bfh[2], bfl[2];
        #pragma unroll
        for (int nf = 0; nf < 2; ++nf) {
            size_t wof = ((((size_t)n * 4 + (nbase + nf)) * NKB + kb) * 64 + l) * 8;
            bfh[nf] = *(const s16x8*)&p.Wh[wof];
            bfl[nf] = *(const s16x8*)&p.Wl[wof];
        }
        int b = mf * 16 + lr;
        s16x8 ah = *(const s16x8*)&sh[nb + b * 64 + koff];
        s16x8 al = *(const s16x8*)&sl[nb + b * 64 + koff];
        #pragma unroll
        for (int nf = 0; nf < 2; ++nf) {
            acc[nf] = __builtin_amdgcn_mfma_f32_16x16x32_bf16(ah, bfh[nf], acc[nf], 0, 0, 0);
            acc[nf] = __builtin_amdgcn_mfma_f32_16x16x32_bf16(ah, bfl[nf], acc[nf], 0, 0, 0);
            acc[nf] = __builtin_amdgcn_mfma_f32_16x16x32_bf16(al, bfh[nf], acc[nf], 0, 0, 0);
        }
    }

    const float* wxn = RANK1 ? (p.wx + (size_t)n * 2 * 64) : p.wx;
    #pragma unroll
    for (int i = 0; i < 4; ++i) {
        int b = mf * 16 + lg * 4 + i;
        float xf = 0.f, txf = 0.f;
        if (RANK1) {
            int idx = n * 768 + p.xoff + b;
            xf = b2f(p.xsh[idx]) + b2f(p.xsl[idx]);
            txf = b2f(p.txh[idx]) + b2f(p.txl[idx]);
        }
        #pragma unroll
        for (int nf = 0; nf < 2; ++nf) {
            int o = (nbase + nf) * 16 + lr;
            float s = acc[nf][i] + p.bias[(size_t)n * 64 + o];
            if (RANK1) s += xf * wxn[o] + txf * wxn[64 + o];
            size_t bo = nb + (size_t)b * 64;
            float hc = tanhf(s);
            float rv = p.rbuf[bo + o];
            float hp = b2f(p.oh[bo + o]) + b2f(p.ol[bo + o]);
            float hn = rv * hp + (1.f - rv) * hc;
            u16 hb = f2b(hn);
            p.oh[bo + o] = hb;
            p.ol[bo + o] = f2b(hn - b2f(hb));
        }
    }
}
template <int K2, bool RANK1>
__global__ __launch_bounds__(256) void k_cellu2(CellP p) {
    d_cellu2<K2, RANK1>(blockIdx.x, blockIdx.y, threadIdx.x, p);
}

// GATE cell split by o-half (round-19 verified)
template <int K2, bool RANK1>
__device__ __forceinline__ void d_cellg2(int n, int ohalf, int tid, const CellP& p) {
    constexpr int NKB = K2 / 32;
    const int w = tid >> 6, l = tid & 63, lr = l & 15, lg = l >> 4;
    const int mbase = (w >> 1) * 2;
    const int nbase = (w & 1) * 2;
    f32x4 acc[2][2];
    #pragma unroll
    for (int a = 0; a < 2; ++a)
        #pragma unroll
        for (int c = 0; c < 2; ++c) acc[a][c] = (f32x4){0.f, 0.f, 0.f, 0.f};
    const size_t nb = (size_t)n * 4096;

    #pragma unroll
    for (int kb = 0; kb < NKB; ++kb) {
        const int sg = kb >> 1;
        const u16* sh = sg == 0 ? p.s0h : sg == 1 ? p.s1h : sg == 2 ? p.s2h : p.s3h;
        const u16* sl = sg == 0 ? p.s0l : sg == 1 ? p.s1l : sg == 2 ? p.s2l : p.s3l;
        const int koff = (kb & 1) * 32 + lg * 8;
        s16x8 bfh[2], bfl[2];
        #pragma unroll
        for (int nf = 0; nf < 2; ++nf) {
            size_t wof = ((((size_t)n * 8 + ohalf * 4 + nbase + nf) * NKB + kb) * 64 + l) * 8;
            bfh[nf] = *(const s16x8*)&p.Wh[wof];
            bfl[nf] = *(const s16x8*)&p.Wl[wof];
        }
        #pragma unroll
        for (int mf = 0; mf < 2; ++mf) {
            int b = (mbase + mf) * 16 + lr;
            s16x8 ah = *(const s16x8*)&sh[nb + b * 64 + koff];
            s16x8 al = *(const s16x8*)&sl[nb + b * 64 + koff];
            #pragma unroll
            for (int nf = 0; nf < 2; ++nf) {
                acc[mf][nf] = __builtin_amdgcn_mfma_f32_16x16x32_bf16(ah, bfh[nf], acc[mf][nf], 0, 0, 0);
                acc[mf][nf] = __builtin_amdgcn_mfma_f32_16x16x32_bf16(ah, bfl[nf], acc[mf][nf], 0, 0, 0);
                acc[mf][nf] = __builtin_amdgcn_mfma_f32_16x16x32_bf16(al, bfh[nf], acc[mf][nf], 0, 0, 0);
            }
        }
    }

    const float* wxn = RANK1 ? (p.wx + (size_t)n * 2 * 128) : p.wx;
    #pragma unroll
    for (int mf = 0; mf < 2; ++mf) {
        #pragma unroll
        for (int i = 0; i < 4; ++i) {
            int b = (mbase + mf) * 16 + lg * 4 + i;
            float xf = 0.f, txf = 0.f;
            if (RANK1) {
                int idx = n * 768 + p.xoff + b;
                xf = b2f(p.xsh[idx]) + b2f(p.xsl[idx]);
                txf = b2f(p.txh[idx]) + b2f(p.txl[idx]);
            }
            #pragma unroll
            for (int nf = 0; nf < 2; ++nf) {
                int o = ohalf * 64 + (nbase + nf) * 16 + lr;
                float s = acc[mf][nf][i] + p.bias[(size_t)n * 128 + o];
                if (RANK1) s += xf * wxn[o] + txf * wxn[128 + o];
                size_t bo = nb + (size_t)b * 64;
                float v = 1.f / (1.f + expf(-s));
                if (o < 64) {
                    float hp = b2f(p.hph[bo + o]) + b2f(p.hpl[bo + o]);
                    float zh = v * hp;
                    u16 hb = f2b(zh);
                    p.oh[bo + o] = hb;
                    p.ol[bo + o] = f2b(zh - b2f(hb));
                } else {
                    p.rbuf[bo + (o - 64)] = v;
                }
            }
        }
    }
}
template <int K2, bool RANK1>
__global__ __launch_bounds__(256) void k_cellg2(CellP p) {
    d_cellg2<K2, RANK1>(blockIdx.x, blockIdx.y, threadIdx.x, p);
}

// ---------------- fused (gmm h1->th1) + (next step's split g0 cell) ----------------
struct FuseArgs {
    const u16* adjb; const u16 *h1h, *h1l; const float *dd, *lmax;
    u16 *th1h, *th1l;
    CellP cell;
};
__global__ __launch_bounds__(256) void k_fuse(FuseArgs a) {
    __shared__ GmmS S;
    const int bid = blockIdx.x;
    if (bid < 1024) {
        d_gmm(bid >> 6, bid & 63, threadIdx.x, a.adjb, a.h1h, a.h1l, a.dd, a.lmax,
              a.th1h, a.th1l, 4096, S);
    } else {
        const int cb = bid - 1024;
        d_cellg2<128, true>(cb >> 1, cb & 1, threadIdx.x, a.cell);
    }
}

// ---------------- end conv ----------------
__global__ __launch_bounds__(256) void k_conv(const u16* __restrict__ hh, const u16* __restrict__ hl,
                                              const float* __restrict__ cw, const float* __restrict__ cb,
                                              float* __restrict__ out) {
    int idx = blockIdx.x * 256 + threadIdx.x;
    int n = idx >> 6, b = idx & 63;
    float hv[64];
    #pragma unroll
    for (int q = 0; q < 8; ++q) {
        s16x8 vh = *(const s16x8*)&hh[(size_t)n * 4096 + b * 64 + q * 8];
        s16x8 vl = *(const s16x8*)&hl[(size_t)n * 4096 + b * 64 + q * 8];
        #pragma unroll
        for (int j = 0; j < 8; ++j) hv[q * 8 + j] = b2f((u16)vh[j]) + b2f((u16)vl[j]);
    }
    #pragma unroll
    for (int t = 0; t < TSEQ; ++t) {
        float s = cb[t];
        #pragma unroll
        for (int j = 0; j < 64; ++j) s += hv[j] * cw[t * 64 + j];
        out[((size_t)b * TSEQ + t) * NN + n] = s;
    }
}

// ---------------- launch ----------------
extern "C" void kernel_launch(void* const* d_in, const int* in_sizes, int n_in,
                              void* d_out, int out_size, void* d_ws, size_t ws_size,
                              hipStream_t stream) {
    const float* gts = (const float*)d_in[0];
    const float* gn  = (const float*)d_in[1];
    const float* E   = (const float*)d_in[2];
    const float* gw0 = (const float*)d_in[3];
    const float* gb0 = (const float*)d_in[4];
    const float* uw0 = (const float*)d_in[5];
    const float* ub0 = (const float*)d_in[6];
    const float* gw1 = (const float*)d_in[7];
    const float* gb1 = (const float*)d_in[8];
    const float* uw1 = (const float*)d_in[9];
    const float* ub1 = (const float*)d_in[10];
    const float* cw  = (const float*)d_in[11];
    const float* cb  = (const float*)d_in[12];
    float* out = (float*)d_out;
    char* ws = (char*)d_ws;

    if (ws_size < WS_BYTES) {
        k_marker<<<1, 64, 0, stream>>>(out, (float)(ws_size >> 20));
        return;
    }

    u16* adjb = (u16*)(ws + B_ADJ);
    float* dd = (float*)(ws + B_DD);
    float* nrm = (float*)(ws + B_NRM);
    float* lmax = (float*)(ws + B_LMAX);
    u16* xsh = (u16*)(ws + B_XSH);
    u16* xsl = (u16*)(ws + B_XSL);
    u16* txh = (u16*)(ws + B_TXH);
    u16* txl = (u16*)(ws + B_TXL);
    u16* h0h  = (u16*)(ws + B_ST + 0 * SZP);
    u16* h0l  = (u16*)(ws + B_ST + 1 * SZP);
    u16* h1h  = (u16*)(ws + B_ST + 2 * SZP);
    u16* h1l  = (u16*)(ws + B_ST + 3 * SZP);
    u16* th0h = (u16*)(ws + B_ST + 4 * SZP);
    u16* th0l = (u16*)(ws + B_ST + 5 * SZP);
    u16* th1h = (u16*)(ws + B_ST + 6 * SZP);
    u16* th1l = (u16*)(ws + B_ST + 7 * SZP);
    u16* zhh  = (u16*)(ws + B_ST + 8 * SZP);
    u16* zhl  = (u16*)(ws + B_ST + 9 * SZP);
    u16* tzh  = (u16*)(ws + B_ST + 10 * SZP);
    u16* tzl  = (u16*)(ws + B_ST + 11 * SZP);
    float* rbuf = (float*)(ws + B_RBUF);
    u16* G0TH = (u16*)(ws + B_G0TH);
    u16* G0TL = (u16*)(ws + B_G0TL);
    u16* U0TH = (u16*)(ws + B_U0TH);
    u16* U0TL = (u16*)(ws + B_U0TL);
    u16* G1TH = (u16*)(ws + B_G1TH);
    u16* G1TL = (u16*)(ws + B_G1TL);
    u16* U1TH = (u16*)(ws + B_U1TH);
    u16* U1TL = (u16*)(ws + B_U1TL);
    float* BG0 = (float*)(ws + B_BG0);
    float* BU0 = (float*)(ws + B_BU0);
    float* BG1 = (float*)(ws + B_BG1);
    float* BU1 = (float*)(ws + B_BU1);
    float* G0X = (float*)(ws + B_G0X);
    float* U0X = (float*)(ws + B_U0X);

    // REPLAY DETERMINISM: zero the ENTIRE used workspace every call (round-8 proven).
    hipMemsetAsync(ws, 0, WS_BYTES, stream);

    k_norm<<<2, 256, 0, stream>>>(E, nrm);
    k_adj<<<NN, 256, 0, stream>>>(E, gn, nrm, adjb, dd);
    k_dmax<<<1, 512, 0, stream>>>(dd, lmax);

    k_xs_bf<<<(NN * TSEQ * BB + 255) / 256, 256, 0, stream>>>(gts, xsh, xsl);
    k_gmm<<<dim3(TSEQ * BB / 64, 16), 256, 0, stream>>>(adjb, xsh, xsl, dd, lmax, txh, txl, TSEQ * BB);

    k_embed2<128, 128, true><<<dim3(32, 4, 4), 256, 0, stream>>>(E, gw0, G0TH, G0TL);
    k_embed2<128, 64, true><<<dim3(32, 4, 2), 256, 0, stream>>>(E, uw0, U0TH, U0TL);
    k_embed2<256, 128, false><<<dim3(32, 8, 4), 256, 0, stream>>>(E, gw1, G1TH, G1TL);
    k_embed2<256, 64, false><<<dim3(32, 8, 2), 256, 0, stream>>>(E, uw1, U1TH, U1TL);
    k_bias<<<512, 256, 0, stream>>>(E, gb0, ub0, gb1, ub1, gw0, uw0,
                                    BG0, BU0, BG1, BU1, G0X, U0X);

    const dim3 gmm_grid(BB * 64 / 64, 16);   // 32x64 tiles -> 1024 blocks
    for (int t = 0; t < TSEQ; ++t) {
        int xoff = t * BB;
        if (t == 0) {
            CellP g0{h0h, h0l, th0h, th0l, nullptr, nullptr, nullptr, nullptr,
                     G0TH, G0TL, BG0, G0X, xsh, xsl, txh, txl, h0h, h0l, rbuf, zhh, zhl, xoff};
            k_cellg2<128, true><<<dim3(512, 2), 256, 0, stream>>>(g0);
        }
        k_gmm<<<gmm_grid, 256, 0, stream>>>(adjb, zhh, zhl, dd, lmax, tzh, tzl, 4096);
        CellP u0{zhh, zhl, tzh, tzl, nullptr, nullptr, nullptr, nullptr,
                 U0TH, U0TL, BU0, U0X, xsh, xsl, txh, txl, nullptr, nullptr, rbuf, h0h, h0l, xoff};
        k_cellu2<128, true><<<dim3(512, 2), 256, 0, stream>>>(u0);
        k_gmm<<<gmm_grid, 256, 0, stream>>>(adjb, h0h, h0l, dd, lmax, th0h, th0l, 4096);
        CellP g1{h0h, h0l, h1h, h1l, th0h, th0l, th1h, th1l,
                 G1TH, G1TL, BG1, nullptr, nullptr, nullptr, nullptr, nullptr, h1h, h1l, rbuf, zhh, zhl, 0};
        k_cellg2<256, false><<<dim3(512, 2), 256, 0, stream>>>(g1);
        k_gmm<<<gmm_grid, 256, 0, stream>>>(adjb, zhh, zhl, dd, lmax, tzh, tzl, 4096);
        CellP u1{h0h, h0l, zhh, zhl, th0h, th0l, tzh, tzl,
                 U1TH, U1TL, BU1, nullptr, nullptr, nullptr, nullptr, nullptr, nullptr, nullptr, rbuf, h1h, h1l, 0};
        k_cellu2<256, false><<<dim3(512, 2), 256, 0, stream>>>(u1);
        if (t + 1 < TSEQ) {
            CellP g0n{h0h, h0l, th0h, th0l, nullptr, nullptr, nullptr, nullptr,
                      G0TH, G0TL, BG0, G0X, xsh, xsl, txh, txl, h0h, h0l, rbuf, zhh, zhl, (t + 1) * BB};
            FuseArgs fa{adjb, h1h, h1l, dd, lmax, th1h, th1l, g0n};
            k_fuse<<<2048, 256, 0, stream>>>(fa);
        }
    }

    k_conv<<<NN * BB / 256, 256, 0, stream>>>(h1h, h1l, cw, cb, out);
}

// Round 22
// 1696.600 us; speedup vs baseline: 1.1040x; 1.1040x over previous
//
#include <hip/hip_runtime.h>
#include <math.h>

#define NN 512
#define TSEQ 12
#define BB 64

typedef unsigned short u16;
typedef short s16x4 __attribute__((ext_vector_type(4)));
typedef short s16x8 __attribute__((ext_vector_type(8)));
typedef float f32x4 __attribute__((ext_vector_type(4)));

__device__ __forceinline__ float b2f(u16 h) { return __uint_as_float(((unsigned)h) << 16); }
__device__ __forceinline__ u16 f2b(float f) {
    unsigned u = __float_as_uint(f);
    return (u16)((u + 0x7FFFu + ((u >> 16) & 1u)) >> 16);
}

// ---------------- workspace layout (bytes) ----------------
constexpr size_t SZP    = (size_t)512 * 4096 * 2;   // one state plane (4 MB)
constexpr size_t B_ADJ  = 0;
constexpr size_t B_DD   = B_ADJ + 524288;
constexpr size_t B_NRM  = B_DD + 2048;
constexpr size_t B_LMAX = B_NRM + 2048;
constexpr size_t B_XSH  = B_LMAX + 256;
constexpr size_t B_XSL  = B_XSH + 786432;
constexpr size_t B_TXH  = B_XSL + 786432;
constexpr size_t B_TXL  = B_TXH + 786432;
constexpr size_t B_ST   = B_TXL + 786432;           // 12 planes
constexpr size_t B_RBUF = B_ST + 12 * SZP;
constexpr size_t B_G0TH = B_RBUF + 8388608;
constexpr size_t B_G0TL = B_G0TH + 16777216;
constexpr size_t B_U0TH = B_G0TL + 16777216;
constexpr size_t B_U0TL = B_U0TH + 8388608;
constexpr size_t B_G1TH = B_U0TL + 8388608;
constexpr size_t B_G1TL = B_G1TH + 33554432;
constexpr size_t B_U1TH = B_G1TL + 33554432;
constexpr size_t B_U1TL = B_U1TH + 16777216;
constexpr size_t B_BG0  = B_U1TL + 16777216;
constexpr size_t B_BU0  = B_BG0 + 262144;
constexpr size_t B_BG1  = B_BU0 + 131072;
constexpr size_t B_BU1  = B_BG1 + 262144;
constexpr size_t B_G0X  = B_BU1 + 131072;
constexpr size_t B_U0X  = B_G0X + 524288;
constexpr size_t WS_BYTES = B_U0X + 262144;         // ~205 MiB

// ---------------- setup kernels ----------------

__global__ void k_marker(float* out, float v) { out[threadIdx.x] = v; }

__global__ void k_norm(const float* __restrict__ E, float* __restrict__ nrm) {
    int n = blockIdx.x * blockDim.x + threadIdx.x;
    if (n < NN) {
        float s = 0.f;
        #pragma unroll
        for (int q = 0; q < 10; ++q) { float e = E[n * 10 + q]; s += e * e; }
        nrm[n] = sqrtf(s);
    }
}

__global__ __launch_bounds__(256) void k_adj(const float* __restrict__ E, const float* __restrict__ gn,
                                             const float* __restrict__ nrm, u16* __restrict__ adjb,
                                             float* __restrict__ dd) {
    __shared__ float En[10];
    __shared__ float red[256];
    int n = blockIdx.x, tid = threadIdx.x;
    if (tid < 10) En[tid] = E[n * 10 + tid];
    __syncthreads();
    float nn = nrm[n];
    float cnt = 0.f;
    for (int m = tid; m < NN; m += 256) {
        float dot = 0.f;
        #pragma unroll
        for (int q = 0; q < 10; ++q) dot += En[q] * E[m * 10 + q];
        float lg = dot / (nn * nrm[m]);
        lg = (lg + 1.f) * 0.5f;
        float g0 = gn[((size_t)n * NN + m) * 2 + 0];
        float g1 = gn[((size_t)n * NN + m) * 2 + 1];
        bool a = ((lg + g0) >= (1.f - lg + g1) && (m != n));
        adjb[(size_t)n * NN + m] = a ? 0x3F80 : 0;
        cnt += a ? 1.f : 0.f;
    }
    red[tid] = cnt;
    __syncthreads();
    for (int s = 128; s > 0; s >>= 1) { if (tid < s) red[tid] += red[tid + s]; __syncthreads(); }
    if (tid == 0) dd[n] = red[0];
}

__global__ void k_dmax(const float* __restrict__ dd, float* __restrict__ lmax) {
    __shared__ float red[512];
    int t = threadIdx.x;
    red[t] = dd[t];
    __syncthreads();
    for (int s = 256; s > 0; s >>= 1) { if (t < s) red[t] = fmaxf(red[t], red[t + s]); __syncthreads(); }
    if (t == 0) lmax[0] = red[0] + (red[0] > 0.f ? 1.f : 0.f);
}

__global__ __launch_bounds__(256) void k_xs_bf(const float* __restrict__ gts, u16* __restrict__ xh,
                                               u16* __restrict__ xl) {
    int idx = blockIdx.x * 256 + threadIdx.x;
    if (idx >= NN * TSEQ * BB) return;
    int n = idx / (TSEQ * BB);
    int rem = idx - n * (TSEQ * BB);
    int t = rem >> 6, b = rem & 63;
    float v = gts[((size_t)b * NN + n) * TSEQ + t];
    u16 hb = f2b(v);
    xh[idx] = hb;
    xl[idx] = f2b(v - b2f(hb));
}

// ---------------- embed v3 (round-16): Wp in LDS + fragment-major output ----------------
template <int K2, int O, bool SHIFT>
__global__ __launch_bounds__(256) void k_embed2(const float* __restrict__ E, const float* __restrict__ Wp,
                                                u16* __restrict__ oh, u16* __restrict__ ol) {
    constexpr int KR = SHIFT ? 130 : K2;
    constexpr int NKB = K2 / 32;
    __shared__ float WpL[10][32][33];
    __shared__ float eL[16][10];
    const int nc = blockIdx.x, kc = blockIdx.y, oc = blockIdx.z;
    const int tid = threadIdx.x;
    const int rb = kc * 32 + (SHIFT ? (kc >= 2 ? 2 : 1) : 0);
    const int ocol = oc * 32;
    const int n0 = nc * 16;

    for (int el = tid; el < 10 * 32 * 32; el += 256) {
        int d = el >> 10;
        int rem = el & 1023;
        int k = rem >> 5, o = rem & 31;
        WpL[d][k][o] = Wp[((size_t)d * KR + rb + k) * O + ocol + o];
    }
    if (tid < 160) eL[tid / 10][tid % 10] = E[(n0 + tid / 10) * 10 + tid % 10];
    __syncthreads();

    const int o2 = tid >> 3;
    const int kv = (tid & 7) * 4;
    const int o = ocol + o2;
    const int lane = ((kv >> 3) << 4) + (o & 15);
    const size_t fragbase =
        ((((size_t)0 * (O / 16) + (o >> 4)) * NKB + kc) * 64 + lane) * 8 + (kv & 7);
    const size_t nstride = (size_t)(O / 16) * NKB * 64 * 8;

    for (int ni = 0; ni < 16; ++ni) {
        float ev[10];
        #pragma unroll
        for (int d = 0; d < 10; ++d) ev[d] = eL[ni][d];
        u16 ph[4], pl[4];
        #pragma unroll
        for (int j = 0; j < 4; ++j) {
            float a = 0.f;
            #pragma unroll
            for (int d = 0; d < 10; ++d) a += ev[d] * WpL[d][kv + j][o2];
            u16 hb = f2b(a);
            ph[j] = hb;
            pl[j] = f2b(a - b2f(hb));
        }
        size_t off = fragbase + (size_t)(n0 + ni) * nstride;
        *(s16x4*)&oh[off] = *(s16x4*)ph;
        *(s16x4*)&ol[off] = *(s16x4*)pl;
    }
}

__global__ __launch_bounds__(256) void k_bias(const float* __restrict__ E, const float* __restrict__ gb0,
                                              const float* __restrict__ ub0, const float* __restrict__ gb1,
                                              const float* __restrict__ ub1, const float* __restrict__ gw0,
                                              const float* __restrict__ uw0,
                                              float* BG0, float* BU0, float* BG1, float* BU1,
                                              float* G0X, float* U0X) {
    __shared__ float e[10];
    int n = blockIdx.x, tid = threadIdx.x;
    if (tid < 10) e[tid] = E[n * 10 + tid];
    __syncthreads();
    if (tid < 128) {
        int o = tid;
        float a0 = 0, a1 = 0, a2 = 0, a3 = 0;
        #pragma unroll
        for (int d = 0; d < 10; ++d) {
            a0 += e[d] * gb0[d * 128 + o];
            a1 += e[d] * gb1[d * 128 + o];
            a2 += e[d] * gw0[((size_t)d * 130 + 0) * 128 + o];
            a3 += e[d] * gw0[((size_t)d * 130 + 65) * 128 + o];
        }
        BG0[n * 128 + o] = a0; BG1[n * 128 + o] = a1;
        G0X[n * 256 + o] = a2; G0X[n * 256 + 128 + o] = a3;
    } else if (tid < 192) {
        int o = tid - 128;
        float a0 = 0, a1 = 0, a2 = 0, a3 = 0;
        #pragma unroll
        for (int d = 0; d < 10; ++d) {
            a0 += e[d] * ub0[d * 64 + o];
            a1 += e[d] * ub1[d * 64 + o];
            a2 += e[d] * uw0[((size_t)d * 130 + 0) * 64 + o];
            a3 += e[d] * uw0[((size_t)d * 130 + 65) * 64 + o];
        }
        BU0[n * 64 + o] = a0; BU1[n * 64 + o] = a1;
        U0X[n * 128 + o] = a2; U0X[n * 128 + 64 + o] = a3;
    }
}

// ---------------- gmm shared + device body (round-17/20 verified 64x64 config) ----------------
// ROUND 22: REVERT of round-21's 32x64 split (regressed +177us: doubled B re-reads,
// 3.1M bank conflicts). This is the round-20 best-measured configuration verbatim.
struct GmmS {
    u16 As[2][64][72];
    u16 Bsh[2][2][64][32];
    u16 Bsl[2][2][64][32];
};

__device__ __forceinline__ void d_gmm(int by, int bx_, int tid,
                                      const u16* __restrict__ A, const u16* __restrict__ Bh,
                                      const u16* __restrict__ Bl, const float* __restrict__ dd,
                                      const float* __restrict__ lmax,
                                      u16* __restrict__ Ch, u16* __restrict__ Cl, int N, GmmS& S) {
    const int w = tid >> 6, l = tid & 63, lr = l & 15, lg = l >> 4;
    const int bm = by * 64, bn = bx_ * 64;
    const int am = tid >> 2, ak = (tid & 3) * 16;
    const int bk = tid >> 3, bn8 = (tid & 7) * 8;
    const int bx = (tid & 7) & 3;
    const int col = ((bk >> 3) ^ bx) * 8 + (bk & 7);
    f32x4 acc[4];
    #pragma unroll
    for (int a = 0; a < 4; ++a) acc[a] = (f32x4){0.f, 0.f, 0.f, 0.f};

    const int nl = w * 16 + lr;
    const int cc = (lg ^ ((nl >> 3) & 3)) * 8;
    const size_t arow = (size_t)(bm + am) * 512;

    s16x8 rA0, rA1, rBh[2], rBl[2];
    rA0 = *(const s16x8*)&A[arow + 0 + ak];
    rA1 = *(const s16x8*)&A[arow + 0 + ak + 8];
    #pragma unroll
    for (int hh = 0; hh < 2; ++hh) {
        rBh[hh] = *(const s16x8*)&Bh[(size_t)(0 + hh * 32 + bk) * N + bn + bn8];
        rBl[hh] = *(const s16x8*)&Bl[(size_t)(0 + hh * 32 + bk) * N + bn + bn8];
    }
    *(s16x8*)&S.As[0][am][ak]     = rA0;
    *(s16x8*)&S.As[0][am][ak + 8] = rA1;
    #pragma unroll
    for (int hh = 0; hh < 2; ++hh) {
        #pragma unroll
        for (int q = 0; q < 8; ++q) {
            S.Bsh[0][hh][bn8 + q][col] = ((const u16*)&rBh[hh])[q];
            S.Bsl[0][hh][bn8 + q][col] = ((const u16*)&rBl[hh])[q];
        }
    }
    __syncthreads();

    for (int k0 = 0; k0 < 512; k0 += 64) {
        const int cur = (k0 >> 6) & 1;
        const bool more = (k0 + 64 < 512);
        if (more) {
            rA0 = *(const s16x8*)&A[arow + k0 + 64 + ak];
            rA1 = *(const s16x8*)&A[arow + k0 + 64 + ak + 8];
            #pragma unroll
            for (int hh = 0; hh < 2; ++hh) {
                rBh[hh] = *(const s16x8*)&Bh[(size_t)(k0 + 64 + hh * 32 + bk) * N + bn + bn8];
                rBl[hh] = *(const s16x8*)&Bl[(size_t)(k0 + 64 + hh * 32 + bk) * N + bn + bn8];
            }
        }
        #pragma unroll
        for (int hh = 0; hh < 2; ++hh) {
            s16x8 bfh = *(const s16x8*)&S.Bsh[cur][hh][nl][cc];
            s16x8 bfl = *(const s16x8*)&S.Bsl[cur][hh][nl][cc];
            #pragma unroll
            for (int mf = 0; mf < 4; ++mf) {
                s16x8 afr = *(const s16x8*)&S.As[cur][mf * 16 + lr][hh * 32 + lg * 8];
                acc[mf] = __builtin_amdgcn_mfma_f32_16x16x32_bf16(afr, bfh, acc[mf], 0, 0, 0);
                acc[mf] = __builtin_amdgcn_mfma_f32_16x16x32_bf16(afr, bfl, acc[mf], 0, 0, 0);
            }
        }
        if (more) {
            const int nxt = cur ^ 1;
            *(s16x8*)&S.As[nxt][am][ak]     = rA0;
            *(s16x8*)&S.As[nxt][am][ak + 8] = rA1;
            #pragma unroll
            for (int hh = 0; hh < 2; ++hh) {
                #pragma unroll
                for (int q = 0; q < 8; ++q) {
                    S.Bsh[nxt][hh][bn8 + q][col] = ((const u16*)&rBh[hh])[q];
                    S.Bsl[nxt][hh][bn8 + q][col] = ((const u16*)&rBl[hh])[q];
                }
            }
        }
        __syncthreads();
    }
    const float lm = lmax[0], alpha = -2.f / lm;
    const int colg = bn + w * 16 + lr;
    #pragma unroll
    for (int mf = 0; mf < 4; ++mf) {
        #pragma unroll
        for (int i = 0; i < 4; ++i) {
            int rowg = bm + mf * 16 + lg * 4 + i;
            size_t off = (size_t)rowg * N + colg;
            float hval = b2f(Bh[off]) + b2f(Bl[off]);
            float beta = 2.f * dd[rowg] / lm - 1.f;
            float v = alpha * acc[mf][i] + beta * hval;
            u16 hb = f2b(v);
            Ch[off] = hb;
            Cl[off] = f2b(v - b2f(hb));
        }
    }
}

__global__ __launch_bounds__(256) void k_gmm(const u16* __restrict__ A, const u16* __restrict__ Bh,
                                             const u16* __restrict__ Bl, const float* __restrict__ dd,
                                             const float* __restrict__ lmax,
                                             u16* __restrict__ Ch, u16* __restrict__ Cl, int N) {
    __shared__ GmmS S;
    d_gmm(blockIdx.y, blockIdx.x, threadIdx.x, A, Bh, Bl, dd, lmax, Ch, Cl, N, S);
}

// ---------------- split-precision MFMA cells ----------------
struct CellP {
    const u16 *s0h, *s0l, *s1h, *s1l, *s2h, *s2l, *s3h, *s3l;
    const u16 *Wh, *Wl;
    const float *bias, *wx;
    const u16 *xsh, *xsl, *txh, *txl;
    const u16 *hph, *hpl;
    float* rbuf;
    u16 *oh, *ol;
    int xoff;
};

// UPDATE cell split by batch-half (round-20 verified)
template <int K2, bool RANK1>
__device__ __forceinline__ void d_cellu2(int n, int mhalf, int tid, const CellP& p) {
    constexpr int NKB = K2 / 32;
    const int w = tid >> 6, l = tid & 63, lr = l & 15, lg = l >> 4;
    const int mf = mhalf * 2 + (w >> 1);
    const int nbase = (w & 1) * 2;
    f32x4 acc[2];
    #pragma unroll
    for (int c = 0; c < 2; ++c) acc[c] = (f32x4){0.f, 0.f, 0.f, 0.f};
    const size_t nb = (size_t)n * 4096;

    #pragma unroll
    for (int kb = 0; kb < NKB; ++kb) {
        const int sg = kb >> 1;
        const u16* sh = sg == 0 ? p.s0h : sg == 1 ? p.s1h : sg == 2 ? p.s2h : p.s3h;
        const u16* sl = sg == 0 ? p.s0l : sg == 1 ? p.s1l : sg == 2 ? p.s2l : p.s3l;
        const int koff = (kb & 1) * 32 + lg * 8;
        s16x8 bfh[2], bfl[2];
        #pragma unroll
        for (int nf = 0; nf < 2; ++nf) {
            size_t wof = ((((size_t)n * 4 + (nbase + nf)) * NKB + kb) * 64 + l) * 8;
            bfh[nf] = *(const s16x8*)&p.Wh[wof];
            bfl[nf] = *(const s16x8*)&p.Wl[wof];
        }
        int b = mf * 16 + lr;
        s16x8 ah = *(const s16x8*)&sh[nb + b * 64 + koff];
        s16x8 al = *(const s16x8*)&sl[nb + b * 64 + koff];
        #pragma unroll
        for (int nf = 0; nf < 2; ++nf) {
            acc[nf] = __builtin_amdgcn_mfma_f32_16x16x32_bf16(ah, bfh[nf], acc[nf], 0, 0, 0);
            acc[nf] = __builtin_amdgcn_mfma_f32_16x16x32_bf16(ah, bfl[nf], acc[nf], 0, 0, 0);
            acc[nf] = __builtin_amdgcn_mfma_f32_16x16x32_bf16(al, bfh[nf], acc[nf], 0, 0, 0);
        }
    }

    const float* wxn = RANK1 ? (p.wx + (size_t)n * 2 * 64) : p.wx;
    #pragma unroll
    for (int i = 0; i < 4; ++i) {
        int b = mf * 16 + lg * 4 + i;
        float xf = 0.f, txf = 0.f;
        if (RANK1) {
            int idx = n * 768 + p.xoff + b;
            xf = b2f(p.xsh[idx]) + b2f(p.xsl[idx]);
            txf = b2f(p.txh[idx]) + b2f(p.txl[idx]);
        }
        #pragma unroll
        for (int nf = 0; nf < 2; ++nf) {
            int o = (nbase + nf) * 16 + lr;
            float s = acc[nf][i] + p.bias[(size_t)n * 64 + o];
            if (RANK1) s += xf * wxn[o] + txf * wxn[64 + o];
            size_t bo = nb + (size_t)b * 64;
            float hc = tanhf(s);
            float rv = p.rbuf[bo + o];
            float hp = b2f(p.oh[bo + o]) + b2f(p.ol[bo + o]);
            float hn = rv * hp + (1.f - rv) * hc;
            u16 hb = f2b(hn);
            p.oh[bo + o] = hb;
            p.ol[bo + o] = f2b(hn - b2f(hb));
        }
    }
}
template <int K2, bool RANK1>
__global__ __launch_bounds__(256) void k_cellu2(CellP p) {
    d_cellu2<K2, RANK1>(blockIdx.x, blockIdx.y, threadIdx.x, p);
}

// GATE cell split by o-half (round-19 verified)
template <int K2, bool RANK1>
__device__ __forceinline__ void d_cellg2(int n, int ohalf, int tid, const CellP& p) {
    constexpr int NKB = K2 / 32;
    const int w = tid >> 6, l = tid & 63, lr = l & 15, lg = l >> 4;
    const int mbase = (w >> 1) * 2;
    const int nbase = (w & 1) * 2;
    f32x4 acc[2][2];
    #pragma unroll
    for (int a = 0; a < 2; ++a)
        #pragma unroll
        for (int c = 0; c < 2; ++c) acc[a][c] = (f32x4){0.f, 0.f, 0.f, 0.f};
    const size_t nb = (size_t)n * 4096;

    #pragma unroll
    for (int kb = 0; kb < NKB; ++kb) {
        const int sg = kb >> 1;
        const u16* sh = sg == 0 ? p.s0h : sg == 1 ? p.s1h : sg == 2 ? p.s2h : p.s3h;
        const u16* sl = sg == 0 ? p.s0l : sg == 1 ? p.s1l : sg == 2 ? p.s2l : p.s3l;
        const int koff = (kb & 1) * 32 + lg * 8;
        s16x8 bfh[2], bfl[2];
        #pragma unroll
        for (int nf = 0; nf < 2; ++nf) {
            size_t wof = ((((size_t)n * 8 + ohalf * 4 + nbase + nf) * NKB + kb) * 64 + l) * 8;
            bfh[nf] = *(const s16x8*)&p.Wh[wof];
            bfl[nf] = *(const s16x8*)&p.Wl[wof];
        }
        #pragma unroll
        for (int mf = 0; mf < 2; ++mf) {
            int b = (mbase + mf) * 16 + lr;
            s16x8 ah = *(const s16x8*)&sh[nb + b * 64 + koff];
            s16x8 al = *(const s16x8*)&sl[nb + b * 64 + koff];
            #pragma unroll
            for (int nf = 0; nf < 2; ++nf) {
                acc[mf][nf] = __builtin_amdgcn_mfma_f32_16x16x32_bf16(ah, bfh[nf], acc[mf][nf], 0, 0, 0);
                acc[mf][nf] = __builtin_amdgcn_mfma_f32_16x16x32_bf16(ah, bfl[nf], acc[mf][nf], 0, 0, 0);
                acc[mf][nf] = __builtin_amdgcn_mfma_f32_16x16x32_bf16(al, bfh[nf], acc[mf][nf], 0, 0, 0);
            }
        }
    }

    const float* wxn = RANK1 ? (p.wx + (size_t)n * 2 * 128) : p.wx;
    #pragma unroll
    for (int mf = 0; mf < 2; ++mf) {
        #pragma unroll
        for (int i = 0; i < 4; ++i) {
            int b = (mbase + mf) * 16 + lg * 4 + i;
            float xf = 0.f, txf = 0.f;
            if (RANK1) {
                int idx = n * 768 + p.xoff + b;
                xf = b2f(p.xsh[idx]) + b2f(p.xsl[idx]);
                txf = b2f(p.txh[idx]) + b2f(p.txl[idx]);
            }
            #pragma unroll
            for (int nf = 0; nf < 2; ++nf) {
                int o = ohalf * 64 + (nbase + nf) * 16 + lr;
                float s = acc[mf][nf][i] + p.bias[(size_t)n * 128 + o];
                if (RANK1) s += xf * wxn[o] + txf * wxn[128 + o];
                size_t bo = nb + (size_t)b * 64;
                float v = 1.f / (1.f + expf(-s));
                if (o < 64) {
                    float hp = b2f(p.hph[bo + o]) + b2f(p.hpl[bo + o]);
                    float zh = v * hp;
                    u16 hb = f2b(zh);
                    p.oh[bo + o] = hb;
                    p.ol[bo + o] = f2b(zh - b2f(hb));
                } else {
                    p.rbuf[bo + (o - 64)] = v;
                }
            }
        }
    }
}
template <int K2, bool RANK1>
__global__ __launch_bounds__(256) void k_cellg2(CellP p) {
    d_cellg2<K2, RANK1>(blockIdx.x, blockIdx.y, threadIdx.x, p);
}

// ---------------- fused (gmm h1->th1) + (next step's split g0 cell) ----------------
struct FuseArgs {
    const u16* adjb; const u16 *h1h, *h1l; const float *dd, *lmax;
    u16 *th1h, *th1l;
    CellP cell;
};
__global__ __launch_bounds__(256) void k_fuse(FuseArgs a) {
    __shared__ GmmS S;
    const int bid = blockIdx.x;
    if (bid < 512) {
        d_gmm(bid >> 6, bid & 63, threadIdx.x, a.adjb, a.h1h, a.h1l, a.dd, a.lmax,
              a.th1h, a.th1l, 4096, S);
    } else {
        const int cb = bid - 512;
        d_cellg2<128, true>(cb >> 1, cb & 1, threadIdx.x, a.cell);
    }
}

// ---------------- end conv ----------------
__global__ __launch_bounds__(256) void k_conv(const u16* __restrict__ hh, const u16* __restrict__ hl,
                                              const float* __restrict__ cw, const float* __restrict__ cb,
                                              float* __restrict__ out) {
    int idx = blockIdx.x * 256 + threadIdx.x;
    int n = idx >> 6, b = idx & 63;
    float hv[64];
    #pragma unroll
    for (int q = 0; q < 8; ++q) {
        s16x8 vh = *(const s16x8*)&hh[(size_t)n * 4096 + b * 64 + q * 8];
        s16x8 vl = *(const s16x8*)&hl[(size_t)n * 4096 + b * 64 + q * 8];
        #pragma unroll
        for (int j = 0; j < 8; ++j) hv[q * 8 + j] = b2f((u16)vh[j]) + b2f((u16)vl[j]);
    }
    #pragma unroll
    for (int t = 0; t < TSEQ; ++t) {
        float s = cb[t];
        #pragma unroll
        for (int j = 0; j < 64; ++j) s += hv[j] * cw[t * 64 + j];
        out[((size_t)b * TSEQ + t) * NN + n] = s;
    }
}

// ---------------- launch ----------------
extern "C" void kernel_launch(void* const* d_in, const int* in_sizes, int n_in,
                              void* d_out, int out_size, void* d_ws, size_t ws_size,
                              hipStream_t stream) {
    const float* gts = (const float*)d_in[0];
    const float* gn  = (const float*)d_in[1];
    const float* E   = (const float*)d_in[2];
    const float* gw0 = (const float*)d_in[3];
    const float* gb0 = (const float*)d_in[4];
    const float* uw0 = (const float*)d_in[5];
    const float* ub0 = (const float*)d_in[6];
    const float* gw1 = (const float*)d_in[7];
    const float* gb1 = (const float*)d_in[8];
    const float* uw1 = (const float*)d_in[9];
    const float* ub1 = (const float*)d_in[10];
    const float* cw  = (const float*)d_in[11];
    const float* cb  = (const float*)d_in[12];
    float* out = (float*)d_out;
    char* ws = (char*)d_ws;

    if (ws_size < WS_BYTES) {
        k_marker<<<1, 64, 0, stream>>>(out, (float)(ws_size >> 20));
        return;
    }

    u16* adjb = (u16*)(ws + B_ADJ);
    float* dd = (float*)(ws + B_DD);
    float* nrm = (float*)(ws + B_NRM);
    float* lmax = (float*)(ws + B_LMAX);
    u16* xsh = (u16*)(ws + B_XSH);
    u16* xsl = (u16*)(ws + B_XSL);
    u16* txh = (u16*)(ws + B_TXH);
    u16* txl = (u16*)(ws + B_TXL);
    u16* h0h  = (u16*)(ws + B_ST + 0 * SZP);
    u16* h0l  = (u16*)(ws + B_ST + 1 * SZP);
    u16* h1h  = (u16*)(ws + B_ST + 2 * SZP);
    u16* h1l  = (u16*)(ws + B_ST + 3 * SZP);
    u16* th0h = (u16*)(ws + B_ST + 4 * SZP);
    u16* th0l = (u16*)(ws + B_ST + 5 * SZP);
    u16* th1h = (u16*)(ws + B_ST + 6 * SZP);
    u16* th1l = (u16*)(ws + B_ST + 7 * SZP);
    u16* zhh  = (u16*)(ws + B_ST + 8 * SZP);
    u16* zhl  = (u16*)(ws + B_ST + 9 * SZP);
    u16* tzh  = (u16*)(ws + B_ST + 10 * SZP);
    u16* tzl  = (u16*)(ws + B_ST + 11 * SZP);
    float* rbuf = (float*)(ws + B_RBUF);
    u16* G0TH = (u16*)(ws + B_G0TH);
    u16* G0TL = (u16*)(ws + B_G0TL);
    u16* U0TH = (u16*)(ws + B_U0TH);
    u16* U0TL = (u16*)(ws + B_U0TL);
    u16* G1TH = (u16*)(ws + B_G1TH);
    u16* G1TL = (u16*)(ws + B_G1TL);
    u16* U1TH = (u16*)(ws + B_U1TH);
    u16* U1TL = (u16*)(ws + B_U1TL);
    float* BG0 = (float*)(ws + B_BG0);
    float* BU0 = (float*)(ws + B_BU0);
    float* BG1 = (float*)(ws + B_BG1);
    float* BU1 = (float*)(ws + B_BU1);
    float* G0X = (float*)(ws + B_G0X);
    float* U0X = (float*)(ws + B_U0X);

    // REPLAY DETERMINISM: zero the ENTIRE used workspace every call (round-8 proven).
    hipMemsetAsync(ws, 0, WS_BYTES, stream);

    k_norm<<<2, 256, 0, stream>>>(E, nrm);
    k_adj<<<NN, 256, 0, stream>>>(E, gn, nrm, adjb, dd);
    k_dmax<<<1, 512, 0, stream>>>(dd, lmax);

    k_xs_bf<<<(NN * TSEQ * BB + 255) / 256, 256, 0, stream>>>(gts, xsh, xsl);
    k_gmm<<<dim3(TSEQ * BB / 64, 8), 256, 0, stream>>>(adjb, xsh, xsl, dd, lmax, txh, txl, TSEQ * BB);

    k_embed2<128, 128, true><<<dim3(32, 4, 4), 256, 0, stream>>>(E, gw0, G0TH, G0TL);
    k_embed2<128, 64, true><<<dim3(32, 4, 2), 256, 0, stream>>>(E, uw0, U0TH, U0TL);
    k_embed2<256, 128, false><<<dim3(32, 8, 4), 256, 0, stream>>>(E, gw1, G1TH, G1TL);
    k_embed2<256, 64, false><<<dim3(32, 8, 2), 256, 0, stream>>>(E, uw1, U1TH, U1TL);
    k_bias<<<512, 256, 0, stream>>>(E, gb0, ub0, gb1, ub1, gw0, uw0,
                                    BG0, BU0, BG1, BU1, G0X, U0X);

    const dim3 gmm_grid(BB * 64 / 64, 8);   // 64x64 tiles -> 512 blocks (round-20 best)
    for (int t = 0; t < TSEQ; ++t) {
        int xoff = t * BB;
        if (t == 0) {
            CellP g0{h0h, h0l, th0h, th0l, nullptr, nullptr, nullptr, nullptr,
                     G0TH, G0TL, BG0, G0X, xsh, xsl, txh, txl, h0h, h0l, rbuf, zhh, zhl, xoff};
            k_cellg2<128, true><<<dim3(512, 2), 256, 0, stream>>>(g0);
        }
        k_gmm<<<gmm_grid, 256, 0, stream>>>(adjb, zhh, zhl, dd, lmax, tzh, tzl, 4096);
        CellP u0{zhh, zhl, tzh, tzl, nullptr, nullptr, nullptr, nullptr,
                 U0TH, U0TL, BU0, U0X, xsh, xsl, txh, txl, nullptr, nullptr, rbuf, h0h, h0l, xoff};
        k_cellu2<128, true><<<dim3(512, 2), 256, 0, stream>>>(u0);
        k_gmm<<<gmm_grid, 256, 0, stream>>>(adjb, h0h, h0l, dd, lmax, th0h, th0l, 4096);
        CellP g1{h0h, h0l, h1h, h1l, th0h, th0l, th1h, th1l,
                 G1TH, G1TL, BG1, nullptr, nullptr, nullptr, nullptr, nullptr, h1h, h1l, rbuf, zhh, zhl, 0};
        k_cellg2<256, false><<<dim3(512, 2), 256, 0, stream>>>(g1);
        k_gmm<<<gmm_grid, 256, 0, stream>>>(adjb, zhh, zhl, dd, lmax, tzh, tzl, 4096);
        CellP u1{h0h, h0l, zhh, zhl, th0h, th0l, tzh, tzl,
                 U1TH, U1TL, BU1, nullptr, nullptr, nullptr, nullptr, nullptr, nullptr, nullptr, rbuf, h1h, h1l, 0};
        k_cellu2<256, false><<<dim3(512, 2), 256, 0, stream>>>(u1);
        if (t + 1 < TSEQ) {
            CellP g0n{h0h, h0l, th0h, th0l, nullptr, nullptr, nullptr, nullptr,
                      G0TH, G0TL, BG0, G0X, xsh, xsl, txh, txl, h0h, h0l, rbuf, zhh, zhl, (t + 1) * BB};
            FuseArgs fa{adjb, h1h, h1l, dd, lmax, th1h, th1l, g0n};
            k_fuse<<<1536, 256, 0, stream>>>(fa);
        }
    }

    k_conv<<<NN * BB / 256, 256, 0, stream>>>(h1h, h1l, cw, cb, out);
}